// Round 6
// baseline (22138.628 us; speedup 1.0000x reference)
//
#include <hip/hip_runtime.h>
#include <hip/hip_bf16.h>

#define H 1024
#define BATCH 128
#define INF 171
#define KXP 256        // padded x width (L1 input / dec feedback)
#define T_TOT 100
#define T_COND 50
#define NDEC 192
#define OUTF 171

typedef __bf16 bf16_t;
typedef __attribute__((ext_vector_type(8))) __bf16 bf16x8;
typedef __attribute__((ext_vector_type(4))) float f32x4;

__device__ __forceinline__ float sigm(float x) { return 1.0f / (1.0f + expf(-x)); }

// ---------------- prep kernels (run every call; idempotent) ----------------

// Split fp32 weights into bf16 hi/lo into a concatenated, gate-interleaved layout:
// dst row r' = 4*j + g  <-  src row g*H + j (if interleave), cols [col_off, col_off+Kcopy)
// of a row of width ldw; zero-pad k >= Kin.
__global__ void prep_weights(const float* __restrict__ W, bf16_t* __restrict__ hi,
                             bf16_t* __restrict__ lo, int rows_out, int rows_valid,
                             int Kin, int Kcopy, int ldw, int col_off, int interleave)
{
    int total = rows_out * Kcopy;
    for (int idx = blockIdx.x * blockDim.x + threadIdx.x; idx < total;
         idx += gridDim.x * blockDim.x) {
        int r = idx / Kcopy;
        int k = idx - r * Kcopy;
        int src = interleave ? ((r & 3) * H + (r >> 2)) : r;
        float v = 0.0f;
        if (k < Kin && src < rows_valid) v = W[(size_t)src * Kin + k];
        bf16_t h = (bf16_t)v;
        size_t d = (size_t)r * ldw + col_off + k;
        hi[d] = h;
        lo[d] = (bf16_t)(v - (float)h);
    }
}

__global__ void prep_bias(const float* __restrict__ bi1, const float* __restrict__ bh1,
                          const float* __restrict__ bi2, const float* __restrict__ bh2,
                          const float* __restrict__ bi3, const float* __restrict__ bh3,
                          const float* __restrict__ bd_in, float* __restrict__ bias3,
                          float* __restrict__ bd_out)
{
    int i = blockIdx.x * blockDim.x + threadIdx.x;
    if (i < 3 * 4096) {
        int L = i >> 12, r = i & 4095;
        int src = (r & 3) * H + (r >> 2);   // interleaved -> source row
        const float* a = (L == 0) ? bi1 : (L == 1) ? bi2 : bi3;
        const float* b = (L == 0) ? bh1 : (L == 1) ? bh2 : bh3;
        bias3[i] = a[src] + b[src];
    } else if (i < 3 * 4096 + NDEC) {
        int n = i - 3 * 4096;
        bd_out[n] = (n < OUTF) ? bd_in[n] : 0.0f;
    }
}

// initial_seq [B][50][INF] -> xseq splits [50][B][KXP] (zero-padded)
__global__ void prep_seq(const float* __restrict__ seq, bf16_t* __restrict__ hi,
                         bf16_t* __restrict__ lo)
{
    int total = T_COND * BATCH * KXP;
    for (int idx = blockIdx.x * blockDim.x + threadIdx.x; idx < total;
         idx += gridDim.x * blockDim.x) {
        int t = idx / (BATCH * KXP);
        int rem = idx - t * (BATCH * KXP);
        int b = rem / KXP;
        int k = rem - b * KXP;
        float v = (k < INF) ? seq[((size_t)b * T_COND + t) * INF + k] : 0.0f;
        bf16_t h = (bf16_t)v;
        hi[idx] = h;
        lo[idx] = (bf16_t)(v - (float)h);
    }
}

// ---------------- fused LSTM layer v2 ----------------
// grid: (64 n-blocks of 64 interleaved gate cols, 4 K-chunks). block: 512 thr = 8 waves.
// Wave layout 2m x 2n x 2k: wave-tile 64x32, BK=64, double-buffered LDS + reg prefetch.
// K-chunk partials -> fp32 pbuf; per-n-block atomic ticket; last WG reduces + cell update.
__global__ __launch_bounds__(512, 2)
void lstm_layer(const bf16_t* __restrict__ xhi, const bf16_t* __restrict__ xlo,
                int ldx, int KX,
                const bf16_t* __restrict__ whi, const bf16_t* __restrict__ wlo, int ldw,
                const bf16_t* __restrict__ hhi, const bf16_t* __restrict__ hlo,
                int nsteps,
                const float* __restrict__ bias, float* __restrict__ cst,
                bf16_t* __restrict__ ohi, bf16_t* __restrict__ olo,
                float* __restrict__ pbuf, unsigned* __restrict__ cnt)
{
    // per buffer: Ah[128][72] Al[128][72] Bh[64][72] Bl[64][72] = 27648 bf16 = 55296 B
    __shared__ __align__(16) bf16_t sm[2][384 * 72];
    __shared__ unsigned s_last;

    const int tid  = threadIdx.x;
    const int lane = tid & 63;
    const int wid  = tid >> 6;
    const int wm = wid & 1, wn = (wid >> 1) & 1, wk = wid >> 2;
    const int nb    = blockIdx.x;            // 0..63
    const int chunk = blockIdx.y;            // 0..3
    const int n0    = nb * 64;
    const int base  = chunk * (nsteps * 64);

    const int r  = tid >> 3;                 // 0..63
    const int c8 = (tid & 7) * 8;

    f32x4 acc[4][2];
#pragma unroll
    for (int i = 0; i < 4; ++i)
#pragma unroll
        for (int j = 0; j < 2; ++j) acc[i][j] = (f32x4){0.f, 0.f, 0.f, 0.f};

    uint4 a0h, a0l, a1h, a1l, b0h, b0l;      // prefetch registers

    auto issue = [&](int s) {
        int kg = base + s * 64;
        const bf16_t *pxh, *pxl; int ld, ko;
        if (kg < KX) { pxh = xhi; pxl = xlo; ld = ldx; ko = kg; }
        else         { pxh = hhi; pxl = hlo; ld = H;   ko = kg - KX; }
        size_t g0 = (size_t)r * ld + ko + c8;
        size_t g1 = (size_t)(r + 64) * ld + ko + c8;
        a0h = *(const uint4*)&pxh[g0];  a0l = *(const uint4*)&pxl[g0];
        a1h = *(const uint4*)&pxh[g1];  a1l = *(const uint4*)&pxl[g1];
        size_t gb = (size_t)(n0 + r) * ldw + kg + c8;
        b0h = *(const uint4*)&whi[gb];  b0l = *(const uint4*)&wlo[gb];
    };
    auto store = [&](int b) {
        bf16_t* Ah = sm[b];           bf16_t* Al = Ah + 128 * 72;
        bf16_t* Bh = Al + 128 * 72;   bf16_t* Bl = Bh + 64 * 72;
        *(uint4*)&Ah[r * 72 + c8] = a0h;  *(uint4*)&Ah[(r + 64) * 72 + c8] = a1h;
        *(uint4*)&Al[r * 72 + c8] = a0l;  *(uint4*)&Al[(r + 64) * 72 + c8] = a1l;
        *(uint4*)&Bh[r * 72 + c8] = b0h;  *(uint4*)&Bl[r * 72 + c8] = b0l;
    };

    const int lr = lane & 15;
    const int lk = (lane >> 4) * 8 + wk * 32;

    issue(0); store(0); __syncthreads();
#pragma unroll 1
    for (int s = 0; s < nsteps; ++s) {
        if (s + 1 < nsteps) issue(s + 1);
        {
            const bf16_t* Ah = sm[s & 1];      const bf16_t* Al = Ah + 128 * 72;
            const bf16_t* Bh = Al + 128 * 72;  const bf16_t* Bl = Bh + 64 * 72;
            bf16x8 ah[4], al[4], bh[2], bl[2];
#pragma unroll
            for (int mt = 0; mt < 4; ++mt) {
                int row = wm * 64 + mt * 16 + lr;
                ah[mt] = *(const bf16x8*)&Ah[row * 72 + lk];
                al[mt] = *(const bf16x8*)&Al[row * 72 + lk];
            }
#pragma unroll
            for (int nt = 0; nt < 2; ++nt) {
                int row = wn * 32 + nt * 16 + lr;
                bh[nt] = *(const bf16x8*)&Bh[row * 72 + lk];
                bl[nt] = *(const bf16x8*)&Bl[row * 72 + lk];
            }
#pragma unroll
            for (int mt = 0; mt < 4; ++mt)
#pragma unroll
                for (int nt = 0; nt < 2; ++nt) {
                    acc[mt][nt] = __builtin_amdgcn_mfma_f32_16x16x32_bf16(ah[mt], bh[nt], acc[mt][nt], 0, 0, 0);
                    acc[mt][nt] = __builtin_amdgcn_mfma_f32_16x16x32_bf16(ah[mt], bl[nt], acc[mt][nt], 0, 0, 0);
                    acc[mt][nt] = __builtin_amdgcn_mfma_f32_16x16x32_bf16(al[mt], bh[nt], acc[mt][nt], 0, 0, 0);
                }
        }
        if (s + 1 < nsteps) { store((s + 1) & 1); __syncthreads(); }
    }
    __syncthreads();

    // intra-WG reduce of the two k-half waves via LDS (G = [128][64] f32, 32 KB)
    float* G = (float*)sm;
    if (wk == 1) {
#pragma unroll
        for (int mt = 0; mt < 4; ++mt)
#pragma unroll
            for (int nt = 0; nt < 2; ++nt)
#pragma unroll
                for (int q = 0; q < 4; ++q)
                    G[(wm * 64 + mt * 16 + (lane >> 4) * 4 + q) * 64 + wn * 32 + nt * 16 + lr] = acc[mt][nt][q];
    }
    __syncthreads();
    if (wk == 0) {
        float* P = pbuf + (size_t)(chunk * 64 + nb) * 8192;
#pragma unroll
        for (int mt = 0; mt < 4; ++mt)
#pragma unroll
            for (int nt = 0; nt < 2; ++nt)
#pragma unroll
                for (int q = 0; q < 4; ++q) {
                    int m = wm * 64 + mt * 16 + (lane >> 4) * 4 + q;
                    int c = wn * 32 + nt * 16 + lr;
                    P[m * 64 + c] = acc[mt][nt][q] + G[m * 64 + c];
                }
    }
    __threadfence();
    __syncthreads();
    if (tid == 0) s_last = atomicAdd(&cnt[nb], 1u);
    __syncthreads();
    if (s_last != 3u) return;
    __threadfence();                       // acquire: make other chunks' partials visible
    if (tid == 0) atomicExch(&cnt[nb], 0u);   // reset for the next step's kernel

    // ---- reduce 4 chunk partials + fused cell update ----
    const int cT = (tid & 15) * 4;
    const int rT = tid >> 4;               // 0..31
    const int j  = nb * 16 + (tid & 15);
    const float4 bb = *(const float4*)&bias[n0 + cT];
#pragma unroll
    for (int rr = 0; rr < 4; ++rr) {
        int m = rT + rr * 32;
        float gx = 0.f, gy = 0.f, gz = 0.f, gw = 0.f;
#pragma unroll
        for (int ch = 0; ch < 4; ++ch) {
            const float4 p = *(const float4*)&pbuf[((size_t)(ch * 64 + nb) * 128 + m) * 64 + cT];
            gx += p.x; gy += p.y; gz += p.z; gw += p.w;
        }
        float iv = sigm(gx + bb.x);
        float fv = sigm(gy + bb.y);
        float gv = tanhf(gz + bb.z);
        float ov = sigm(gw + bb.w);
        size_t ci = (size_t)m * H + j;
        float cn = fv * cst[ci] + iv * gv;
        cst[ci] = cn;
        float hn = ov * tanhf(cn);
        bf16_t hh2 = (bf16_t)hn;
        ohi[ci] = hh2;
        olo[ci] = (bf16_t)(hn - (float)hh2);
    }
}

// ---------------- decoder GEMM (MFMA, 3-product) + output + feedback split ----
// grid: (6 n-blocks of 32, 4 m-blocks of 32), block: 64 threads (1 wave)
__global__ __launch_bounds__(64)
void dec_kernel(const bf16_t* __restrict__ hhi, const bf16_t* __restrict__ hlo,
                const bf16_t* __restrict__ whi, const bf16_t* __restrict__ wlo,
                const float* __restrict__ bd, float* __restrict__ out, int t,
                bf16_t* __restrict__ xfhi, bf16_t* __restrict__ xflo)
{
    __shared__ __align__(16) bf16_t sm[4 * 32 * 72];
    bf16_t* sAh = sm;
    bf16_t* sAl = sAh + 32 * 72;
    bf16_t* sBh = sAl + 32 * 72;
    bf16_t* sBl = sBh + 32 * 72;

    const int tid = threadIdx.x;         // == lane
    const int m0 = blockIdx.y * 32;
    const int n0 = blockIdx.x * 32;

    f32x4 acc[2][2];
#pragma unroll
    for (int i = 0; i < 2; ++i)
#pragma unroll
        for (int j = 0; j < 2; ++j) acc[i][j] = (f32x4){0.f, 0.f, 0.f, 0.f};

    const int c8 = (tid & 7) * 8;
    const int r0 = tid >> 3;             // 0..7
    const int lr = tid & 15;
    const int lk = (tid >> 4) * 8;

#pragma unroll 1
    for (int k0 = 0; k0 < H; k0 += 64) {
        __syncthreads();
#pragma unroll
        for (int rr = 0; rr < 4; ++rr) {
            int r = r0 + rr * 8;
            size_t ga = (size_t)(m0 + r) * H + k0 + c8;
            *(uint4*)&sAh[r * 72 + c8] = *(const uint4*)&hhi[ga];
            *(uint4*)&sAl[r * 72 + c8] = *(const uint4*)&hlo[ga];
            size_t gb = (size_t)(n0 + r) * H + k0 + c8;
            *(uint4*)&sBh[r * 72 + c8] = *(const uint4*)&whi[gb];
            *(uint4*)&sBl[r * 72 + c8] = *(const uint4*)&wlo[gb];
        }
        __syncthreads();
#pragma unroll
        for (int kk = 0; kk < 64; kk += 32) {
            bf16x8 ah[2], al[2], bh[2], bl[2];
#pragma unroll
            for (int mt = 0; mt < 2; ++mt) {
                ah[mt] = *(const bf16x8*)&sAh[(mt * 16 + lr) * 72 + kk + lk];
                al[mt] = *(const bf16x8*)&sAl[(mt * 16 + lr) * 72 + kk + lk];
            }
#pragma unroll
            for (int nt = 0; nt < 2; ++nt) {
                bh[nt] = *(const bf16x8*)&sBh[(nt * 16 + lr) * 72 + kk + lk];
                bl[nt] = *(const bf16x8*)&sBl[(nt * 16 + lr) * 72 + kk + lk];
            }
#pragma unroll
            for (int mt = 0; mt < 2; ++mt)
#pragma unroll
                for (int nt = 0; nt < 2; ++nt) {
                    acc[mt][nt] = __builtin_amdgcn_mfma_f32_16x16x32_bf16(ah[mt], bh[nt], acc[mt][nt], 0, 0, 0);
                    acc[mt][nt] = __builtin_amdgcn_mfma_f32_16x16x32_bf16(ah[mt], bl[nt], acc[mt][nt], 0, 0, 0);
                    acc[mt][nt] = __builtin_amdgcn_mfma_f32_16x16x32_bf16(al[mt], bh[nt], acc[mt][nt], 0, 0, 0);
                }
        }
    }
#pragma unroll
    for (int mt = 0; mt < 2; ++mt)
#pragma unroll
        for (int nt = 0; nt < 2; ++nt)
#pragma unroll
            for (int q = 0; q < 4; ++q) {
                int brow = m0 + mt * 16 + (tid >> 4) * 4 + q;
                int n = n0 + nt * 16 + lr;
                float v = acc[mt][nt][q] + bd[n];
                float vf = (n < OUTF) ? v : 0.0f;
                if (n < OUTF) out[((size_t)brow * T_TOT + t) * OUTF + n] = v;
                bf16_t hh = (bf16_t)vf;
                xfhi[(size_t)brow * KXP + n] = hh;
                xflo[(size_t)brow * KXP + n] = (bf16_t)(vf - (float)hh);
            }
}

// ---------------- host launch ----------------
extern "C" void kernel_launch(void* const* d_in, const int* in_sizes, int n_in,
                              void* d_out, int out_size, void* d_ws, size_t ws_size,
                              hipStream_t stream)
{
    (void)in_sizes; (void)n_in; (void)out_size;
    const float* seq   = (const float*)d_in[0];
    const float* Wih1  = (const float*)d_in[1];
    const float* Whh1  = (const float*)d_in[2];
    const float* bih1  = (const float*)d_in[3];
    const float* bhh1  = (const float*)d_in[4];
    const float* Wih2  = (const float*)d_in[5];
    const float* Whh2  = (const float*)d_in[6];
    const float* bih2  = (const float*)d_in[7];
    const float* bhh2  = (const float*)d_in[8];
    const float* Wih3  = (const float*)d_in[9];
    const float* Whh3  = (const float*)d_in[10];
    const float* bih3  = (const float*)d_in[11];
    const float* bhh3  = (const float*)d_in[12];
    const float* Wdec  = (const float*)d_in[13];
    const float* bdecI = (const float*)d_in[14];
    float* out = (float*)d_out;

    size_t off = 0;
    auto alloc = [&](size_t bytes) -> void* {
        void* p = (char*)d_ws + off;
        off += (bytes + 255) & ~(size_t)255;
        return p;
    };

    // ---- zero region (one contiguous memset): c[3], h splits buf0, counters, xf ----
    float* c0 = (float*)alloc((size_t)BATCH * H * 4);
    float* c1 = (float*)alloc((size_t)BATCH * H * 4);
    float* c2 = (float*)alloc((size_t)BATCH * H * 4);
    bf16_t *hh_[3][2], *hl_[3][2];
    for (int L = 0; L < 3; ++L) {
        hh_[L][0] = (bf16_t*)alloc((size_t)BATCH * H * 2);
        hl_[L][0] = (bf16_t*)alloc((size_t)BATCH * H * 2);
    }
    unsigned* cnt = (unsigned*)alloc(64 * 4);
    bf16_t* xfh = (bf16_t*)alloc((size_t)BATCH * KXP * 2);   // pad cols stay 0
    bf16_t* xfl = (bf16_t*)alloc((size_t)BATCH * KXP * 2);
    size_t zero_bytes = off;

    for (int L = 0; L < 3; ++L) {
        hh_[L][1] = (bf16_t*)alloc((size_t)BATCH * H * 2);
        hl_[L][1] = (bf16_t*)alloc((size_t)BATCH * H * 2);
    }
    float* bias3 = (float*)alloc(3 * 4096 * 4);
    float* bd    = (float*)alloc(NDEC * 4);
    float* pbuf  = (float*)alloc((size_t)4 * 64 * 128 * 64 * 4);   // 8.4 MB

    const int LDW1 = KXP + H;    // 1280
    const int LDW2 = 2 * H;      // 2048
    bf16_t* w1h = (bf16_t*)alloc((size_t)4096 * LDW1 * 2);
    bf16_t* w1l = (bf16_t*)alloc((size_t)4096 * LDW1 * 2);
    bf16_t* w2h = (bf16_t*)alloc((size_t)4096 * LDW2 * 2);
    bf16_t* w2l = (bf16_t*)alloc((size_t)4096 * LDW2 * 2);
    bf16_t* w3h = (bf16_t*)alloc((size_t)4096 * LDW2 * 2);
    bf16_t* w3l = (bf16_t*)alloc((size_t)4096 * LDW2 * 2);
    bf16_t* wdh = (bf16_t*)alloc((size_t)NDEC * H * 2);
    bf16_t* wdl = (bf16_t*)alloc((size_t)NDEC * H * 2);
    bf16_t* xsh = (bf16_t*)alloc((size_t)T_COND * BATCH * KXP * 2);
    bf16_t* xsl = (bf16_t*)alloc((size_t)T_COND * BATCH * KXP * 2);

    if (ws_size < off) return;  // insufficient scratch -> visible as absmax fail

    hipMemsetAsync(c0, 0, zero_bytes, stream);

    // ---- weight / bias / sequence prep (every call) ----
    prep_weights<<<dim3(2048), 256, 0, stream>>>(Wih1, w1h, w1l, 4096, 4096, INF, KXP, LDW1, 0, 1);
    prep_weights<<<dim3(8192), 256, 0, stream>>>(Whh1, w1h, w1l, 4096, 4096, H, H, LDW1, KXP, 1);
    prep_weights<<<dim3(8192), 256, 0, stream>>>(Wih2, w2h, w2l, 4096, 4096, H, H, LDW2, 0, 1);
    prep_weights<<<dim3(8192), 256, 0, stream>>>(Whh2, w2h, w2l, 4096, 4096, H, H, LDW2, H, 1);
    prep_weights<<<dim3(8192), 256, 0, stream>>>(Wih3, w3h, w3l, 4096, 4096, H, H, LDW2, 0, 1);
    prep_weights<<<dim3(8192), 256, 0, stream>>>(Whh3, w3h, w3l, 4096, 4096, H, H, LDW2, H, 1);
    prep_weights<<<dim3(1024), 256, 0, stream>>>(Wdec, wdh, wdl, NDEC, OUTF, H, H, H, 0, 0);
    prep_bias<<<dim3(49), 256, 0, stream>>>(bih1, bhh1, bih2, bhh2, bih3, bhh3, bdecI, bias3, bd);
    prep_seq<<<dim3(2048), 256, 0, stream>>>(seq, xsh, xsl);

    // ---- 100 sequential steps ----
    for (int t = 0; t < T_TOT; ++t) {
        const bf16_t *xh, *xl;
        if (t < T_COND) {
            xh = xsh + (size_t)t * BATCH * KXP;
            xl = xsl + (size_t)t * BATCH * KXP;
        } else {
            xh = xfh;
            xl = xfl;
        }
        int pr = t & 1, pw = pr ^ 1;
        lstm_layer<<<dim3(64, 4), 512, 0, stream>>>(
            xh, xl, KXP, KXP, w1h, w1l, LDW1,
            hh_[0][pr], hl_[0][pr], (KXP + H) / 256,
            bias3, c0, hh_[0][pw], hl_[0][pw], pbuf, cnt);
        lstm_layer<<<dim3(64, 4), 512, 0, stream>>>(
            hh_[0][pw], hl_[0][pw], H, H, w2h, w2l, LDW2,
            hh_[1][pr], hl_[1][pr], 8,
            bias3 + 4096, c1, hh_[1][pw], hl_[1][pw], pbuf, cnt);
        lstm_layer<<<dim3(64, 4), 512, 0, stream>>>(
            hh_[1][pw], hl_[1][pw], H, H, w3h, w3l, LDW2,
            hh_[2][pr], hl_[2][pr], 8,
            bias3 + 8192, c2, hh_[2][pw], hl_[2][pw], pbuf, cnt);
        dec_kernel<<<dim3(6, 4), 64, 0, stream>>>(
            hh_[2][pw], hl_[2][pw], wdh, wdl, bd, out, t, xfh, xfl);
    }
}

// Round 8
// 22119.501 us; speedup vs baseline: 1.0009x; 1.0009x over previous
//
#include <hip/hip_runtime.h>
#include <hip/hip_bf16.h>

#define H 1024
#define BATCH 128
#define INF 171
#define KXP 256        // padded x width (L1 input / dec feedback)
#define T_TOT 100
#define T_COND 50
#define NDEC 192
#define OUTF 171

typedef __bf16 bf16_t;
typedef __attribute__((ext_vector_type(8))) __bf16 bf16x8;
typedef __attribute__((ext_vector_type(4))) float f32x4;

__device__ __forceinline__ float sigm(float x) { return 1.0f / (1.0f + expf(-x)); }

// async global->LDS, 16B per lane; LDS dest is wave-uniform base + lane*16
#define GLD16(gp, lp) __builtin_amdgcn_global_load_lds( \
    (const __attribute__((address_space(1))) void*)(gp), \
    (__attribute__((address_space(3))) void*)(lp), 16, 0, 0)

// ---------------- prep kernels (run every call; idempotent) ----------------

__global__ void prep_weights(const float* __restrict__ W, bf16_t* __restrict__ hi,
                             bf16_t* __restrict__ lo, int rows_out, int rows_valid,
                             int Kin, int Kcopy, int ldw, int col_off, int interleave)
{
    int total = rows_out * Kcopy;
    for (int idx = blockIdx.x * blockDim.x + threadIdx.x; idx < total;
         idx += gridDim.x * blockDim.x) {
        int r = idx / Kcopy;
        int k = idx - r * Kcopy;
        int src = interleave ? ((r & 3) * H + (r >> 2)) : r;
        float v = 0.0f;
        if (k < Kin && src < rows_valid) v = W[(size_t)src * Kin + k];
        bf16_t h = (bf16_t)v;
        size_t d = (size_t)r * ldw + col_off + k;
        hi[d] = h;
        lo[d] = (bf16_t)(v - (float)h);
    }
}

__global__ void prep_bias(const float* __restrict__ bi1, const float* __restrict__ bh1,
                          const float* __restrict__ bi2, const float* __restrict__ bh2,
                          const float* __restrict__ bi3, const float* __restrict__ bh3,
                          const float* __restrict__ bd_in, float* __restrict__ bias3,
                          float* __restrict__ bd_out)
{
    int i = blockIdx.x * blockDim.x + threadIdx.x;
    if (i < 3 * 4096) {
        int L = i >> 12, r = i & 4095;
        int src = (r & 3) * H + (r >> 2);   // interleaved -> source row
        const float* a = (L == 0) ? bi1 : (L == 1) ? bi2 : bi3;
        const float* b = (L == 0) ? bh1 : (L == 1) ? bh2 : bh3;
        bias3[i] = a[src] + b[src];
    } else if (i < 3 * 4096 + NDEC) {
        int n = i - 3 * 4096;
        bd_out[n] = (n < OUTF) ? bd_in[n] : 0.0f;
    }
}

__global__ void prep_seq(const float* __restrict__ seq, bf16_t* __restrict__ hi,
                         bf16_t* __restrict__ lo)
{
    int total = T_COND * BATCH * KXP;
    for (int idx = blockIdx.x * blockDim.x + threadIdx.x; idx < total;
         idx += gridDim.x * blockDim.x) {
        int t = idx / (BATCH * KXP);
        int rem = idx - t * (BATCH * KXP);
        int b = rem / KXP;
        int k = rem - b * KXP;
        float v = (k < INF) ? seq[((size_t)b * T_COND + t) * INF + k] : 0.0f;
        bf16_t h = (bf16_t)v;
        hi[idx] = h;
        lo[idx] = (bf16_t)(v - (float)h);
    }
}

// ---------------- fused LSTM layer v3 ----------------
// grid: (64 n-blocks of 64 interleaved gate cols, 4 K-chunks). block: 512 thr = 8 waves.
// Wave layout 2m x 2n x 2k; BK=64. Staging via async global_load_lds (16B) into
// double-buffered LINEAR-row LDS tiles; bank conflicts fixed by XOR swizzle applied
// via inverse-permuted per-lane GLOBAL source + swizzled ds_read (rule 21).
// K-chunk partials -> fp32 pbuf; per-n-block atomic ticket; last WG reduces + cell update.
__global__ __launch_bounds__(512, 2)
void lstm_layer(const bf16_t* __restrict__ xhi, const bf16_t* __restrict__ xlo,
                int ldx, int KX,
                const bf16_t* __restrict__ whi, const bf16_t* __restrict__ wlo, int ldw,
                const bf16_t* __restrict__ hhi, const bf16_t* __restrict__ hlo,
                int nsteps,
                const float* __restrict__ bias, float* __restrict__ cst,
                bf16_t* __restrict__ ohi, bf16_t* __restrict__ olo,
                float* __restrict__ pbuf, unsigned* __restrict__ cnt)
{
    // per buffer (elements): Ah[128][64]=8192, Al 8192, Bh[64][64]=4096, Bl 4096 -> 24576
    __shared__ __align__(16) bf16_t sm[2 * 24576];   // 96 KB
    __shared__ unsigned s_last;

    const int tid  = threadIdx.x;
    const int lane = tid & 63;
    const int wid  = tid >> 6;
    const int wm = wid & 1, wn = (wid >> 1) & 1, wk = wid >> 2;
    const int nb    = blockIdx.x;            // 0..63
    const int chunk = blockIdx.y;            // 0..3
    const int n0    = nb * 64;
    const int base  = chunk * (nsteps * 64);

    const int lrow  = lane >> 3;                                   // 0..7 row in 8-row group
    const int lperm = (((lane & 7) ^ (lrow & 7)) << 3);            // source col permute (elems)

    f32x4 acc[4][2];
#pragma unroll
    for (int i = 0; i < 4; ++i)
#pragma unroll
        for (int j = 0; j < 2; ++j) acc[i][j] = (f32x4){0.f, 0.f, 0.f, 0.f};

    // 48 stage tasks per k-step (Ah:0-15, Al:16-31, Bh:32-39, Bl:40-47), 6 per wave.
    auto stage = [&](int s, int buf) {
        const int kg = base + s * 64;
        const bf16_t *pAh, *pAl; int ldA, ka;
        if (kg < KX) { pAh = xhi; pAl = xlo; ldA = ldx; ka = kg; }
        else         { pAh = hhi; pAl = hlo; ldA = H;   ka = kg - KX; }
        bf16_t* lb = sm + buf * 24576;
#pragma unroll
        for (int i = 0; i < 6; ++i) {
            const int task = wid * 6 + i;
            const bf16_t* src; int ldS, row0, kc; bf16_t* dst;
            if (task < 16)      { src = pAh; ldS = ldA; row0 = task * 8;             kc = ka; dst = lb + task * 512; }
            else if (task < 32) { src = pAl; ldS = ldA; row0 = (task - 16) * 8;      kc = ka; dst = lb + 8192 + (task - 16) * 512; }
            else if (task < 40) { src = whi; ldS = ldw; row0 = n0 + (task - 32) * 8; kc = kg; dst = lb + 16384 + (task - 32) * 512; }
            else                { src = wlo; ldS = ldw; row0 = n0 + (task - 40) * 8; kc = kg; dst = lb + 20480 + (task - 40) * 512; }
            const bf16_t* g = src + (size_t)(row0 + lrow) * ldS + kc + lperm;
            GLD16(g, dst);
        }
    };

    const int lr  = lane & 15;
    const int lkE = ((lane >> 4) << 3) + wk * 32;   // element col within 64

    stage(0, 0);
    __syncthreads();                                 // drains vmcnt -> buf0 ready
#pragma unroll 1
    for (int s = 0; s < nsteps; ++s) {
        if (s + 1 < nsteps) stage(s + 1, (s + 1) & 1);
        const bf16_t* Ah = sm + (s & 1) * 24576;
        const bf16_t* Al = Ah + 8192;
        const bf16_t* Bh = Ah + 16384;
        const bf16_t* Bl = Ah + 20480;
        bf16x8 ahf[4], alf[4], bhf[2], blf[2];
#pragma unroll
        for (int mt = 0; mt < 4; ++mt) {
            int row = wm * 64 + mt * 16 + lr;
            int cp  = lkE ^ ((row & 7) << 3);
            ahf[mt] = *(const bf16x8*)&Ah[row * 64 + cp];
            alf[mt] = *(const bf16x8*)&Al[row * 64 + cp];
        }
#pragma unroll
        for (int nt = 0; nt < 2; ++nt) {
            int row = wn * 32 + nt * 16 + lr;
            int cp  = lkE ^ ((row & 7) << 3);
            bhf[nt] = *(const bf16x8*)&Bh[row * 64 + cp];
            blf[nt] = *(const bf16x8*)&Bl[row * 64 + cp];
        }
#pragma unroll
        for (int mt = 0; mt < 4; ++mt)
#pragma unroll
            for (int nt = 0; nt < 2; ++nt) {
                acc[mt][nt] = __builtin_amdgcn_mfma_f32_16x16x32_bf16(ahf[mt], bhf[nt], acc[mt][nt], 0, 0, 0);
                acc[mt][nt] = __builtin_amdgcn_mfma_f32_16x16x32_bf16(ahf[mt], blf[nt], acc[mt][nt], 0, 0, 0);
                acc[mt][nt] = __builtin_amdgcn_mfma_f32_16x16x32_bf16(alf[mt], bhf[nt], acc[mt][nt], 0, 0, 0);
            }
        __syncthreads();   // drains vmcnt (next buffer staged) + protects buffer reuse
    }

    // intra-WG reduce of the two k-half waves via LDS (G = [128][64] f32, 32 KB)
    float* G = (float*)sm;
    if (wk == 1) {
#pragma unroll
        for (int mt = 0; mt < 4; ++mt)
#pragma unroll
            for (int nt = 0; nt < 2; ++nt)
#pragma unroll
                for (int q = 0; q < 4; ++q)
                    G[(wm * 64 + mt * 16 + (lane >> 4) * 4 + q) * 64 + wn * 32 + nt * 16 + lr] = acc[mt][nt][q];
    }
    __syncthreads();
    if (wk == 0) {
        float* P = pbuf + (size_t)(chunk * 64 + nb) * 8192;
#pragma unroll
        for (int mt = 0; mt < 4; ++mt)
#pragma unroll
            for (int nt = 0; nt < 2; ++nt)
#pragma unroll
                for (int q = 0; q < 4; ++q) {
                    int m = wm * 64 + mt * 16 + (lane >> 4) * 4 + q;
                    int c = wn * 32 + nt * 16 + lr;
                    P[m * 64 + c] = acc[mt][nt][q] + G[m * 64 + c];
                }
    }
    __threadfence();
    __syncthreads();
    if (tid == 0) s_last = atomicAdd(&cnt[nb], 1u);
    __syncthreads();
    if (s_last != 3u) return;
    __threadfence();                       // acquire: make other chunks' partials visible
    if (tid == 0) atomicExch(&cnt[nb], 0u);   // reset for the next step's kernel

    // ---- reduce 4 chunk partials + fused cell update ----
    const int cT = (tid & 15) * 4;
    const int rT = tid >> 4;               // 0..31
    const int j  = nb * 16 + (tid & 15);
    const float4 bb = *(const float4*)&bias[n0 + cT];
#pragma unroll
    for (int rr = 0; rr < 4; ++rr) {
        int m = rT + rr * 32;
        float gx = 0.f, gy = 0.f, gz = 0.f, gw = 0.f;
#pragma unroll
        for (int ch = 0; ch < 4; ++ch) {
            const float4 p = *(const float4*)&pbuf[((size_t)(ch * 64 + nb) * 128 + m) * 64 + cT];
            gx += p.x; gy += p.y; gz += p.z; gw += p.w;
        }
        float iv = sigm(gx + bb.x);
        float fv = sigm(gy + bb.y);
        float gv = tanhf(gz + bb.z);
        float ov = sigm(gw + bb.w);
        size_t ci = (size_t)m * H + j;
        float cn = fv * cst[ci] + iv * gv;
        cst[ci] = cn;
        float hn = ov * tanhf(cn);
        bf16_t hh2 = (bf16_t)hn;
        ohi[ci] = hh2;
        olo[ci] = (bf16_t)(hn - (float)hh2);
    }
}

// ---------------- decoder GEMM (MFMA, 3-product) + output + feedback split ----
// grid: (6 n-blocks of 32, 4 m-blocks of 32), block: 64 threads (1 wave)
__global__ __launch_bounds__(64)
void dec_kernel(const bf16_t* __restrict__ hhi, const bf16_t* __restrict__ hlo,
                const bf16_t* __restrict__ whi, const bf16_t* __restrict__ wlo,
                const float* __restrict__ bd, float* __restrict__ out, int t,
                bf16_t* __restrict__ xfhi, bf16_t* __restrict__ xflo)
{
    __shared__ __align__(16) bf16_t sm[4 * 32 * 72];
    bf16_t* sAh = sm;
    bf16_t* sAl = sAh + 32 * 72;
    bf16_t* sBh = sAl + 32 * 72;
    bf16_t* sBl = sBh + 32 * 72;

    const int tid = threadIdx.x;         // == lane
    const int m0 = blockIdx.y * 32;
    const int n0 = blockIdx.x * 32;

    f32x4 acc[2][2];
#pragma unroll
    for (int i = 0; i < 2; ++i)
#pragma unroll
        for (int j = 0; j < 2; ++j) acc[i][j] = (f32x4){0.f, 0.f, 0.f, 0.f};

    const int c8 = (tid & 7) * 8;
    const int r0 = tid >> 3;             // 0..7
    const int lr = tid & 15;
    const int lk = (tid >> 4) * 8;

#pragma unroll 1
    for (int k0 = 0; k0 < H; k0 += 64) {
        __syncthreads();
#pragma unroll
        for (int rr = 0; rr < 4; ++rr) {
            int r = r0 + rr * 8;
            size_t ga = (size_t)(m0 + r) * H + k0 + c8;
            *(uint4*)&sAh[r * 72 + c8] = *(const uint4*)&hhi[ga];
            *(uint4*)&sAl[r * 72 + c8] = *(const uint4*)&hlo[ga];
            size_t gb = (size_t)(n0 + r) * H + k0 + c8;
            *(uint4*)&sBh[r * 72 + c8] = *(const uint4*)&whi[gb];
            *(uint4*)&sBl[r * 72 + c8] = *(const uint4*)&wlo[gb];
        }
        __syncthreads();
#pragma unroll
        for (int kk = 0; kk < 64; kk += 32) {
            bf16x8 ah[2], al[2], bh[2], bl[2];
#pragma unroll
            for (int mt = 0; mt < 2; ++mt) {
                ah[mt] = *(const bf16x8*)&sAh[(mt * 16 + lr) * 72 + kk + lk];
                al[mt] = *(const bf16x8*)&sAl[(mt * 16 + lr) * 72 + kk + lk];
            }
#pragma unroll
            for (int nt = 0; nt < 2; ++nt) {
                bh[nt] = *(const bf16x8*)&sBh[(nt * 16 + lr) * 72 + kk + lk];
                bl[nt] = *(const bf16x8*)&sBl[(nt * 16 + lr) * 72 + kk + lk];
            }
#pragma unroll
            for (int mt = 0; mt < 2; ++mt)
#pragma unroll
                for (int nt = 0; nt < 2; ++nt) {
                    acc[mt][nt] = __builtin_amdgcn_mfma_f32_16x16x32_bf16(ah[mt], bh[nt], acc[mt][nt], 0, 0, 0);
                    acc[mt][nt] = __builtin_amdgcn_mfma_f32_16x16x32_bf16(ah[mt], bl[nt], acc[mt][nt], 0, 0, 0);
                    acc[mt][nt] = __builtin_amdgcn_mfma_f32_16x16x32_bf16(al[mt], bh[nt], acc[mt][nt], 0, 0, 0);
                }
        }
    }
#pragma unroll
    for (int mt = 0; mt < 2; ++mt)
#pragma unroll
        for (int nt = 0; nt < 2; ++nt)
#pragma unroll
            for (int q = 0; q < 4; ++q) {
                int brow = m0 + mt * 16 + (tid >> 4) * 4 + q;
                int n = n0 + nt * 16 + lr;
                float v = acc[mt][nt][q] + bd[n];
                float vf = (n < OUTF) ? v : 0.0f;
                if (n < OUTF) out[((size_t)brow * T_TOT + t) * OUTF + n] = v;
                bf16_t hh = (bf16_t)vf;
                xfhi[(size_t)brow * KXP + n] = hh;
                xflo[(size_t)brow * KXP + n] = (bf16_t)(vf - (float)hh);
            }
}

// ---------------- host launch ----------------
extern "C" void kernel_launch(void* const* d_in, const int* in_sizes, int n_in,
                              void* d_out, int out_size, void* d_ws, size_t ws_size,
                              hipStream_t stream)
{
    (void)in_sizes; (void)n_in; (void)out_size;
    const float* seq   = (const float*)d_in[0];
    const float* Wih1  = (const float*)d_in[1];
    const float* Whh1  = (const float*)d_in[2];
    const float* bih1  = (const float*)d_in[3];
    const float* bhh1  = (const float*)d_in[4];
    const float* Wih2  = (const float*)d_in[5];
    const float* Whh2  = (const float*)d_in[6];
    const float* bih2  = (const float*)d_in[7];
    const float* bhh2  = (const float*)d_in[8];
    const float* Wih3  = (const float*)d_in[9];
    const float* Whh3  = (const float*)d_in[10];
    const float* bih3  = (const float*)d_in[11];
    const float* bhh3  = (const float*)d_in[12];
    const float* Wdec  = (const float*)d_in[13];
    const float* bdecI = (const float*)d_in[14];
    float* out = (float*)d_out;

    size_t off = 0;
    auto alloc = [&](size_t bytes) -> void* {
        void* p = (char*)d_ws + off;
        off += (bytes + 255) & ~(size_t)255;
        return p;
    };

    // ---- zero region (one contiguous memset): c[3], h splits buf0, counters, xf ----
    float* c0 = (float*)alloc((size_t)BATCH * H * 4);
    float* c1 = (float*)alloc((size_t)BATCH * H * 4);
    float* c2 = (float*)alloc((size_t)BATCH * H * 4);
    bf16_t *hh_[3][2], *hl_[3][2];
    for (int L = 0; L < 3; ++L) {
        hh_[L][0] = (bf16_t*)alloc((size_t)BATCH * H * 2);
        hl_[L][0] = (bf16_t*)alloc((size_t)BATCH * H * 2);
    }
    unsigned* cnt = (unsigned*)alloc(64 * 4);
    bf16_t* xfh = (bf16_t*)alloc((size_t)BATCH * KXP * 2);   // pad cols stay 0
    bf16_t* xfl = (bf16_t*)alloc((size_t)BATCH * KXP * 2);
    size_t zero_bytes = off;

    for (int L = 0; L < 3; ++L) {
        hh_[L][1] = (bf16_t*)alloc((size_t)BATCH * H * 2);
        hl_[L][1] = (bf16_t*)alloc((size_t)BATCH * H * 2);
    }
    float* bias3 = (float*)alloc(3 * 4096 * 4);
    float* bd    = (float*)alloc(NDEC * 4);
    float* pbuf  = (float*)alloc((size_t)4 * 64 * 128 * 64 * 4);   // 8.4 MB

    const int LDW1 = KXP + H;    // 1280
    const int LDW2 = 2 * H;      // 2048
    bf16_t* w1h = (bf16_t*)alloc((size_t)4096 * LDW1 * 2);
    bf16_t* w1l = (bf16_t*)alloc((size_t)4096 * LDW1 * 2);
    bf16_t* w2h = (bf16_t*)alloc((size_t)4096 * LDW2 * 2);
    bf16_t* w2l = (bf16_t*)alloc((size_t)4096 * LDW2 * 2);
    bf16_t* w3h = (bf16_t*)alloc((size_t)4096 * LDW2 * 2);
    bf16_t* w3l = (bf16_t*)alloc((size_t)4096 * LDW2 * 2);
    bf16_t* wdh = (bf16_t*)alloc((size_t)NDEC * H * 2);
    bf16_t* wdl = (bf16_t*)alloc((size_t)NDEC * H * 2);
    bf16_t* xsh = (bf16_t*)alloc((size_t)T_COND * BATCH * KXP * 2);
    bf16_t* xsl = (bf16_t*)alloc((size_t)T_COND * BATCH * KXP * 2);

    if (ws_size < off) return;  // insufficient scratch -> visible as absmax fail

    hipMemsetAsync(c0, 0, zero_bytes, stream);

    // ---- weight / bias / sequence prep (every call) ----
    prep_weights<<<dim3(2048), 256, 0, stream>>>(Wih1, w1h, w1l, 4096, 4096, INF, KXP, LDW1, 0, 1);
    prep_weights<<<dim3(8192), 256, 0, stream>>>(Whh1, w1h, w1l, 4096, 4096, H, H, LDW1, KXP, 1);
    prep_weights<<<dim3(8192), 256, 0, stream>>>(Wih2, w2h, w2l, 4096, 4096, H, H, LDW2, 0, 1);
    prep_weights<<<dim3(8192), 256, 0, stream>>>(Whh2, w2h, w2l, 4096, 4096, H, H, LDW2, H, 1);
    prep_weights<<<dim3(8192), 256, 0, stream>>>(Wih3, w3h, w3l, 4096, 4096, H, H, LDW2, 0, 1);
    prep_weights<<<dim3(8192), 256, 0, stream>>>(Whh3, w3h, w3l, 4096, 4096, H, H, LDW2, H, 1);
    prep_weights<<<dim3(1024), 256, 0, stream>>>(Wdec, wdh, wdl, NDEC, OUTF, H, H, H, 0, 0);
    prep_bias<<<dim3(49), 256, 0, stream>>>(bih1, bhh1, bih2, bhh2, bih3, bhh3, bdecI, bias3, bd);
    prep_seq<<<dim3(2048), 256, 0, stream>>>(seq, xsh, xsl);

    // ---- 100 sequential steps ----
    for (int t = 0; t < T_TOT; ++t) {
        const bf16_t *xh, *xl;
        if (t < T_COND) {
            xh = xsh + (size_t)t * BATCH * KXP;
            xl = xsl + (size_t)t * BATCH * KXP;
        } else {
            xh = xfh;
            xl = xfl;
        }
        int pr = t & 1, pw = pr ^ 1;
        lstm_layer<<<dim3(64, 4), 512, 0, stream>>>(
            xh, xl, KXP, KXP, w1h, w1l, LDW1,
            hh_[0][pr], hl_[0][pr], (KXP + H) / 256,
            bias3, c0, hh_[0][pw], hl_[0][pw], pbuf, cnt);
        lstm_layer<<<dim3(64, 4), 512, 0, stream>>>(
            hh_[0][pw], hl_[0][pw], H, H, w2h, w2l, LDW2,
            hh_[1][pr], hl_[1][pr], 8,
            bias3 + 4096, c1, hh_[1][pw], hl_[1][pw], pbuf, cnt);
        lstm_layer<<<dim3(64, 4), 512, 0, stream>>>(
            hh_[1][pw], hl_[1][pw], H, H, w3h, w3l, LDW2,
            hh_[2][pr], hl_[2][pr], 8,
            bias3 + 8192, c2, hh_[2][pw], hl_[2][pw], pbuf, cnt);
        dec_kernel<<<dim3(6, 4), 64, 0, stream>>>(
            hh_[2][pw], hl_[2][pw], wdh, wdl, bd, out, t, xfh, xfl);
    }
}

// Round 9
// 7804.989 us; speedup vs baseline: 2.8365x; 2.8340x over previous
//
#include <hip/hip_runtime.h>
#include <hip/hip_bf16.h>

#define H 1024
#define BATCH 128
#define INF 171
#define KXP 256        // padded x width (L1 input / dec feedback)
#define T_TOT 100
#define T_COND 50
#define NDEC 192
#define OUTF 171

typedef __bf16 bf16_t;
typedef __attribute__((ext_vector_type(8))) __bf16 bf16x8;
typedef __attribute__((ext_vector_type(4))) float f32x4;

__device__ __forceinline__ float sigm(float x) { return 1.0f / (1.0f + expf(-x)); }

// async global->LDS, 16B per lane; LDS dest is wave-uniform base + lane*16
#define GLD16(gp, lp) __builtin_amdgcn_global_load_lds( \
    (const __attribute__((address_space(1))) void*)(gp), \
    (__attribute__((address_space(3))) void*)(lp), 16, 0, 0)

// ---------------- prep kernels (run every call; idempotent) ----------------

__global__ void prep_weights(const float* __restrict__ W, bf16_t* __restrict__ hi,
                             bf16_t* __restrict__ lo, int rows_out, int rows_valid,
                             int Kin, int Kcopy, int ldw, int col_off, int interleave)
{
    int total = rows_out * Kcopy;
    for (int idx = blockIdx.x * blockDim.x + threadIdx.x; idx < total;
         idx += gridDim.x * blockDim.x) {
        int r = idx / Kcopy;
        int k = idx - r * Kcopy;
        int src = interleave ? ((r & 3) * H + (r >> 2)) : r;
        float v = 0.0f;
        if (k < Kin && src < rows_valid) v = W[(size_t)src * Kin + k];
        bf16_t h = (bf16_t)v;
        size_t d = (size_t)r * ldw + col_off + k;
        hi[d] = h;
        lo[d] = (bf16_t)(v - (float)h);
    }
}

__global__ void prep_bias(const float* __restrict__ bi1, const float* __restrict__ bh1,
                          const float* __restrict__ bi2, const float* __restrict__ bh2,
                          const float* __restrict__ bi3, const float* __restrict__ bh3,
                          const float* __restrict__ bd_in, float* __restrict__ bias3,
                          float* __restrict__ bd_out)
{
    int i = blockIdx.x * blockDim.x + threadIdx.x;
    if (i < 3 * 4096) {
        int L = i >> 12, r = i & 4095;
        int src = (r & 3) * H + (r >> 2);   // interleaved -> source row
        const float* a = (L == 0) ? bi1 : (L == 1) ? bi2 : bi3;
        const float* b = (L == 0) ? bh1 : (L == 1) ? bh2 : bh3;
        bias3[i] = a[src] + b[src];
    } else if (i < 3 * 4096 + NDEC) {
        int n = i - 3 * 4096;
        bd_out[n] = (n < OUTF) ? bd_in[n] : 0.0f;
    }
}

__global__ void prep_seq(const float* __restrict__ seq, bf16_t* __restrict__ hi,
                         bf16_t* __restrict__ lo)
{
    int total = T_COND * BATCH * KXP;
    for (int idx = blockIdx.x * blockDim.x + threadIdx.x; idx < total;
         idx += gridDim.x * blockDim.x) {
        int t = idx / (BATCH * KXP);
        int rem = idx - t * (BATCH * KXP);
        int b = rem / KXP;
        int k = rem - b * KXP;
        float v = (k < INF) ? seq[((size_t)b * T_COND + t) * INF + k] : 0.0f;
        bf16_t h = (bf16_t)v;
        hi[idx] = h;
        lo[idx] = (bf16_t)(v - (float)h);
    }
}

// ---------------- LSTM gates GEMM (v4: no cross-WG protocol) ----------------
// grid: (64 n-blocks of 64 interleaved gate cols, 4 K-chunks). block: 512 thr = 8 waves.
// Wave layout 2m x 2n x 2k; BK=64. Async global_load_lds staging into double-buffered
// linear LDS; rule-21 swizzle (inverse-permuted global source + XOR'd ds_read).
// Writes fp32 partials to pbuf; kernel END provides ordering for the cell kernel.
__global__ __launch_bounds__(512, 2)
void lstm_gemm(const bf16_t* __restrict__ xhi, const bf16_t* __restrict__ xlo,
               int ldx, int KX,
               const bf16_t* __restrict__ whi, const bf16_t* __restrict__ wlo, int ldw,
               const bf16_t* __restrict__ hhi, const bf16_t* __restrict__ hlo,
               int nsteps, float* __restrict__ pbuf)
{
    // per buffer (elements): Ah[128][64]=8192, Al 8192, Bh[64][64]=4096, Bl 4096 -> 24576
    __shared__ __align__(16) bf16_t sm[2 * 24576];   // 96 KB

    const int tid  = threadIdx.x;
    const int lane = tid & 63;
    const int wid  = tid >> 6;
    const int wm = wid & 1, wn = (wid >> 1) & 1, wk = wid >> 2;
    const int nb    = blockIdx.x;            // 0..63
    const int chunk = blockIdx.y;            // 0..3
    const int n0    = nb * 64;
    const int base  = chunk * (nsteps * 64);

    const int lrow  = lane >> 3;                                   // 0..7 row in 8-row group
    const int lperm = (((lane & 7) ^ (lrow & 7)) << 3);            // source col permute (elems)

    f32x4 acc[4][2];
#pragma unroll
    for (int i = 0; i < 4; ++i)
#pragma unroll
        for (int j = 0; j < 2; ++j) acc[i][j] = (f32x4){0.f, 0.f, 0.f, 0.f};

    // 48 stage tasks per k-step (Ah:0-15, Al:16-31, Bh:32-39, Bl:40-47), 6 per wave.
    auto stage = [&](int s, int buf) {
        const int kg = base + s * 64;
        const bf16_t *pAh, *pAl; int ldA, ka;
        if (kg < KX) { pAh = xhi; pAl = xlo; ldA = ldx; ka = kg; }
        else         { pAh = hhi; pAl = hlo; ldA = H;   ka = kg - KX; }
        bf16_t* lb = sm + buf * 24576;
#pragma unroll
        for (int i = 0; i < 6; ++i) {
            const int task = wid * 6 + i;
            const bf16_t* src; int ldS, row0, kc; bf16_t* dst;
            if (task < 16)      { src = pAh; ldS = ldA; row0 = task * 8;             kc = ka; dst = lb + task * 512; }
            else if (task < 32) { src = pAl; ldS = ldA; row0 = (task - 16) * 8;      kc = ka; dst = lb + 8192 + (task - 16) * 512; }
            else if (task < 40) { src = whi; ldS = ldw; row0 = n0 + (task - 32) * 8; kc = kg; dst = lb + 16384 + (task - 32) * 512; }
            else                { src = wlo; ldS = ldw; row0 = n0 + (task - 40) * 8; kc = kg; dst = lb + 20480 + (task - 40) * 512; }
            const bf16_t* g = src + (size_t)(row0 + lrow) * ldS + kc + lperm;
            GLD16(g, dst);
        }
    };

    const int lr  = lane & 15;
    const int lkE = ((lane >> 4) << 3) + wk * 32;   // element col within 64

    stage(0, 0);
    __syncthreads();                                 // drains vmcnt -> buf0 ready
#pragma unroll 1
    for (int s = 0; s < nsteps; ++s) {
        if (s + 1 < nsteps) stage(s + 1, (s + 1) & 1);
        const bf16_t* Ah = sm + (s & 1) * 24576;
        const bf16_t* Al = Ah + 8192;
        const bf16_t* Bh = Ah + 16384;
        const bf16_t* Bl = Ah + 20480;
        bf16x8 ahf[4], alf[4], bhf[2], blf[2];
#pragma unroll
        for (int mt = 0; mt < 4; ++mt) {
            int row = wm * 64 + mt * 16 + lr;
            int cp  = lkE ^ ((row & 7) << 3);
            ahf[mt] = *(const bf16x8*)&Ah[row * 64 + cp];
            alf[mt] = *(const bf16x8*)&Al[row * 64 + cp];
        }
#pragma unroll
        for (int nt = 0; nt < 2; ++nt) {
            int row = wn * 32 + nt * 16 + lr;
            int cp  = lkE ^ ((row & 7) << 3);
            bhf[nt] = *(const bf16x8*)&Bh[row * 64 + cp];
            blf[nt] = *(const bf16x8*)&Bl[row * 64 + cp];
        }
#pragma unroll
        for (int mt = 0; mt < 4; ++mt)
#pragma unroll
            for (int nt = 0; nt < 2; ++nt) {
                acc[mt][nt] = __builtin_amdgcn_mfma_f32_16x16x32_bf16(ahf[mt], bhf[nt], acc[mt][nt], 0, 0, 0);
                acc[mt][nt] = __builtin_amdgcn_mfma_f32_16x16x32_bf16(ahf[mt], blf[nt], acc[mt][nt], 0, 0, 0);
                acc[mt][nt] = __builtin_amdgcn_mfma_f32_16x16x32_bf16(alf[mt], bhf[nt], acc[mt][nt], 0, 0, 0);
            }
        __syncthreads();   // drains vmcnt (next buffer staged) + protects buffer reuse
    }

    // intra-WG reduce of the two k-half waves via LDS (G = [128][64] f32, 32 KB)
    float* G = (float*)sm;
    if (wk == 1) {
#pragma unroll
        for (int mt = 0; mt < 4; ++mt)
#pragma unroll
            for (int nt = 0; nt < 2; ++nt)
#pragma unroll
                for (int q = 0; q < 4; ++q)
                    G[(wm * 64 + mt * 16 + (lane >> 4) * 4 + q) * 64 + wn * 32 + nt * 16 + lr] = acc[mt][nt][q];
    }
    __syncthreads();
    if (wk == 0) {
        float* P = pbuf + (size_t)(chunk * 64 + nb) * 8192;
#pragma unroll
        for (int mt = 0; mt < 4; ++mt)
#pragma unroll
            for (int nt = 0; nt < 2; ++nt)
#pragma unroll
                for (int q = 0; q < 4; ++q) {
                    int m = wm * 64 + mt * 16 + (lane >> 4) * 4 + q;
                    int c = wn * 32 + nt * 16 + lr;
                    P[m * 64 + c] = acc[mt][nt][q] + G[m * 64 + c];
                }
    }
    // kernel end = release; next dispatch (lstm_cell) sees the partials
}

// ---------------- LSTM cell update (v4) ----------------
// grid: 64 WGs (one per 64-col n-block) x 256 thr. Sums 4 chunk partials + bias,
// applies sigmoid/tanh cell update, writes h hi/lo splits + c.
__global__ __launch_bounds__(256)
void lstm_cell(const float* __restrict__ pbuf, const float* __restrict__ bias,
               float* __restrict__ cst, bf16_t* __restrict__ ohi, bf16_t* __restrict__ olo)
{
    const int nb = blockIdx.x;             // 0..63
    const int jj = threadIdx.x & 15;       // j within n-block
    const int mr = threadIdx.x >> 4;       // 0..15
    const int j  = nb * 16 + jj;           // global j in [0,1024)
    const float4 bb = *(const float4*)&bias[nb * 64 + jj * 4];
#pragma unroll
    for (int rr = 0; rr < 8; ++rr) {
        int m = mr + rr * 16;
        float gx = 0.f, gy = 0.f, gz = 0.f, gw = 0.f;
#pragma unroll
        for (int ch = 0; ch < 4; ++ch) {
            const float4 p = *(const float4*)&pbuf[(size_t)(ch * 64 + nb) * 8192 + m * 64 + jj * 4];
            gx += p.x; gy += p.y; gz += p.z; gw += p.w;
        }
        float iv = sigm(gx + bb.x);
        float fv = sigm(gy + bb.y);
        float gv = tanhf(gz + bb.z);
        float ov = sigm(gw + bb.w);
        size_t ci = (size_t)m * H + j;
        float cn = fv * cst[ci] + iv * gv;
        cst[ci] = cn;
        float hn = ov * tanhf(cn);
        bf16_t hh2 = (bf16_t)hn;
        ohi[ci] = hh2;
        olo[ci] = (bf16_t)(hn - (float)hh2);
    }
}

// ---------------- decoder GEMM (MFMA, 3-product) + output + feedback split ----
// grid: (6 n-blocks of 32, 4 m-blocks of 32), block: 64 threads (1 wave)
__global__ __launch_bounds__(64)
void dec_kernel(const bf16_t* __restrict__ hhi, const bf16_t* __restrict__ hlo,
                const bf16_t* __restrict__ whi, const bf16_t* __restrict__ wlo,
                const float* __restrict__ bd, float* __restrict__ out, int t,
                bf16_t* __restrict__ xfhi, bf16_t* __restrict__ xflo)
{
    __shared__ __align__(16) bf16_t sm[4 * 32 * 72];
    bf16_t* sAh = sm;
    bf16_t* sAl = sAh + 32 * 72;
    bf16_t* sBh = sAl + 32 * 72;
    bf16_t* sBl = sBh + 32 * 72;

    const int tid = threadIdx.x;         // == lane
    const int m0 = blockIdx.y * 32;
    const int n0 = blockIdx.x * 32;

    f32x4 acc[2][2];
#pragma unroll
    for (int i = 0; i < 2; ++i)
#pragma unroll
        for (int j = 0; j < 2; ++j) acc[i][j] = (f32x4){0.f, 0.f, 0.f, 0.f};

    const int c8 = (tid & 7) * 8;
    const int r0 = tid >> 3;             // 0..7
    const int lr = tid & 15;
    const int lk = (tid >> 4) * 8;

#pragma unroll 1
    for (int k0 = 0; k0 < H; k0 += 64) {
        __syncthreads();
#pragma unroll
        for (int rr = 0; rr < 4; ++rr) {
            int r = r0 + rr * 8;
            size_t ga = (size_t)(m0 + r) * H + k0 + c8;
            *(uint4*)&sAh[r * 72 + c8] = *(const uint4*)&hhi[ga];
            *(uint4*)&sAl[r * 72 + c8] = *(const uint4*)&hlo[ga];
            size_t gb = (size_t)(n0 + r) * H + k0 + c8;
            *(uint4*)&sBh[r * 72 + c8] = *(const uint4*)&whi[gb];
            *(uint4*)&sBl[r * 72 + c8] = *(const uint4*)&wlo[gb];
        }
        __syncthreads();
#pragma unroll
        for (int kk = 0; kk < 64; kk += 32) {
            bf16x8 ah[2], al[2], bh[2], bl[2];
#pragma unroll
            for (int mt = 0; mt < 2; ++mt) {
                ah[mt] = *(const bf16x8*)&sAh[(mt * 16 + lr) * 72 + kk + lk];
                al[mt] = *(const bf16x8*)&sAl[(mt * 16 + lr) * 72 + kk + lk];
            }
#pragma unroll
            for (int nt = 0; nt < 2; ++nt) {
                bh[nt] = *(const bf16x8*)&sBh[(nt * 16 + lr) * 72 + kk + lk];
                bl[nt] = *(const bf16x8*)&sBl[(nt * 16 + lr) * 72 + kk + lk];
            }
#pragma unroll
            for (int mt = 0; mt < 2; ++mt)
#pragma unroll
                for (int nt = 0; nt < 2; ++nt) {
                    acc[mt][nt] = __builtin_amdgcn_mfma_f32_16x16x32_bf16(ah[mt], bh[nt], acc[mt][nt], 0, 0, 0);
                    acc[mt][nt] = __builtin_amdgcn_mfma_f32_16x16x32_bf16(ah[mt], bl[nt], acc[mt][nt], 0, 0, 0);
                    acc[mt][nt] = __builtin_amdgcn_mfma_f32_16x16x32_bf16(al[mt], bh[nt], acc[mt][nt], 0, 0, 0);
                }
        }
    }
#pragma unroll
    for (int mt = 0; mt < 2; ++mt)
#pragma unroll
        for (int nt = 0; nt < 2; ++nt)
#pragma unroll
            for (int q = 0; q < 4; ++q) {
                int brow = m0 + mt * 16 + (tid >> 4) * 4 + q;
                int n = n0 + nt * 16 + lr;
                float v = acc[mt][nt][q] + bd[n];
                float vf = (n < OUTF) ? v : 0.0f;
                if (n < OUTF) out[((size_t)brow * T_TOT + t) * OUTF + n] = v;
                bf16_t hh = (bf16_t)vf;
                xfhi[(size_t)brow * KXP + n] = hh;
                xflo[(size_t)brow * KXP + n] = (bf16_t)(vf - (float)hh);
            }
}

// ---------------- host launch ----------------
extern "C" void kernel_launch(void* const* d_in, const int* in_sizes, int n_in,
                              void* d_out, int out_size, void* d_ws, size_t ws_size,
                              hipStream_t stream)
{
    (void)in_sizes; (void)n_in; (void)out_size;
    const float* seq   = (const float*)d_in[0];
    const float* Wih1  = (const float*)d_in[1];
    const float* Whh1  = (const float*)d_in[2];
    const float* bih1  = (const float*)d_in[3];
    const float* bhh1  = (const float*)d_in[4];
    const float* Wih2  = (const float*)d_in[5];
    const float* Whh2  = (const float*)d_in[6];
    const float* bih2  = (const float*)d_in[7];
    const float* bhh2  = (const float*)d_in[8];
    const float* Wih3  = (const float*)d_in[9];
    const float* Whh3  = (const float*)d_in[10];
    const float* bih3  = (const float*)d_in[11];
    const float* bhh3  = (const float*)d_in[12];
    const float* Wdec  = (const float*)d_in[13];
    const float* bdecI = (const float*)d_in[14];
    float* out = (float*)d_out;

    size_t off = 0;
    auto alloc = [&](size_t bytes) -> void* {
        void* p = (char*)d_ws + off;
        off += (bytes + 255) & ~(size_t)255;
        return p;
    };

    // ---- zero region (one contiguous memset): c[3], h splits buf0, xf ----
    float* c0 = (float*)alloc((size_t)BATCH * H * 4);
    float* c1 = (float*)alloc((size_t)BATCH * H * 4);
    float* c2 = (float*)alloc((size_t)BATCH * H * 4);
    bf16_t *hh_[3][2], *hl_[3][2];
    for (int L = 0; L < 3; ++L) {
        hh_[L][0] = (bf16_t*)alloc((size_t)BATCH * H * 2);
        hl_[L][0] = (bf16_t*)alloc((size_t)BATCH * H * 2);
    }
    bf16_t* xfh = (bf16_t*)alloc((size_t)BATCH * KXP * 2);   // pad cols stay 0
    bf16_t* xfl = (bf16_t*)alloc((size_t)BATCH * KXP * 2);
    size_t zero_bytes = off;

    for (int L = 0; L < 3; ++L) {
        hh_[L][1] = (bf16_t*)alloc((size_t)BATCH * H * 2);
        hl_[L][1] = (bf16_t*)alloc((size_t)BATCH * H * 2);
    }
    float* bias3 = (float*)alloc(3 * 4096 * 4);
    float* bd    = (float*)alloc(NDEC * 4);
    float* pbuf  = (float*)alloc((size_t)4 * 64 * 128 * 64 * 4);   // 8.4 MB

    const int LDW1 = KXP + H;    // 1280
    const int LDW2 = 2 * H;      // 2048
    bf16_t* w1h = (bf16_t*)alloc((size_t)4096 * LDW1 * 2);
    bf16_t* w1l = (bf16_t*)alloc((size_t)4096 * LDW1 * 2);
    bf16_t* w2h = (bf16_t*)alloc((size_t)4096 * LDW2 * 2);
    bf16_t* w2l = (bf16_t*)alloc((size_t)4096 * LDW2 * 2);
    bf16_t* w3h = (bf16_t*)alloc((size_t)4096 * LDW2 * 2);
    bf16_t* w3l = (bf16_t*)alloc((size_t)4096 * LDW2 * 2);
    bf16_t* wdh = (bf16_t*)alloc((size_t)NDEC * H * 2);
    bf16_t* wdl = (bf16_t*)alloc((size_t)NDEC * H * 2);
    bf16_t* xsh = (bf16_t*)alloc((size_t)T_COND * BATCH * KXP * 2);
    bf16_t* xsl = (bf16_t*)alloc((size_t)T_COND * BATCH * KXP * 2);

    if (ws_size < off) return;  // insufficient scratch -> visible as absmax fail

    hipMemsetAsync(c0, 0, zero_bytes, stream);

    // ---- weight / bias / sequence prep (every call) ----
    prep_weights<<<dim3(2048), 256, 0, stream>>>(Wih1, w1h, w1l, 4096, 4096, INF, KXP, LDW1, 0, 1);
    prep_weights<<<dim3(8192), 256, 0, stream>>>(Whh1, w1h, w1l, 4096, 4096, H, H, LDW1, KXP, 1);
    prep_weights<<<dim3(8192), 256, 0, stream>>>(Wih2, w2h, w2l, 4096, 4096, H, H, LDW2, 0, 1);
    prep_weights<<<dim3(8192), 256, 0, stream>>>(Whh2, w2h, w2l, 4096, 4096, H, H, LDW2, H, 1);
    prep_weights<<<dim3(8192), 256, 0, stream>>>(Wih3, w3h, w3l, 4096, 4096, H, H, LDW2, 0, 1);
    prep_weights<<<dim3(8192), 256, 0, stream>>>(Whh3, w3h, w3l, 4096, 4096, H, H, LDW2, H, 1);
    prep_weights<<<dim3(1024), 256, 0, stream>>>(Wdec, wdh, wdl, NDEC, OUTF, H, H, H, 0, 0);
    prep_bias<<<dim3(49), 256, 0, stream>>>(bih1, bhh1, bih2, bhh2, bih3, bhh3, bdecI, bias3, bd);
    prep_seq<<<dim3(2048), 256, 0, stream>>>(seq, xsh, xsl);

    // ---- 100 sequential steps ----
    for (int t = 0; t < T_TOT; ++t) {
        const bf16_t *xh, *xl;
        if (t < T_COND) {
            xh = xsh + (size_t)t * BATCH * KXP;
            xl = xsl + (size_t)t * BATCH * KXP;
        } else {
            xh = xfh;
            xl = xfl;
        }
        int pr = t & 1, pw = pr ^ 1;
        lstm_gemm<<<dim3(64, 4), 512, 0, stream>>>(
            xh, xl, KXP, KXP, w1h, w1l, LDW1,
            hh_[0][pr], hl_[0][pr], (KXP + H) / 256, pbuf);
        lstm_cell<<<dim3(64), 256, 0, stream>>>(pbuf, bias3, c0, hh_[0][pw], hl_[0][pw]);
        lstm_gemm<<<dim3(64, 4), 512, 0, stream>>>(
            hh_[0][pw], hl_[0][pw], H, H, w2h, w2l, LDW2,
            hh_[1][pr], hl_[1][pr], 8, pbuf);
        lstm_cell<<<dim3(64), 256, 0, stream>>>(pbuf, bias3 + 4096, c1, hh_[1][pw], hl_[1][pw]);
        lstm_gemm<<<dim3(64, 4), 512, 0, stream>>>(
            hh_[1][pw], hl_[1][pw], H, H, w3h, w3l, LDW2,
            hh_[2][pr], hl_[2][pr], 8, pbuf);
        lstm_cell<<<dim3(64), 256, 0, stream>>>(pbuf, bias3 + 8192, c2, hh_[2][pw], hl_[2][pw]);
        dec_kernel<<<dim3(6, 4), 64, 0, stream>>>(
            hh_[2][pw], hl_[2][pw], wdh, wdl, bd, out, t, xfh, xfl);
    }
}